// Round 9
// baseline (302.263 us; speedup 1.0000x reference)
//
#include <hip/hip_runtime.h>
#include <math.h>

#define SEQ 4096
#define NH  8
#define DIM 64
// 32 (n,h) pairs total: n=4, h=8

__device__ __forceinline__ float elu1(float x) {
    // jax.nn.elu(x)+1: branchless — exp(min(x,0)) + max(x,0)
    return __expf(fminf(x, 0.0f)) + fmaxf(x, 0.0f);
}

// ---------------- Phase 1: partial KV (64x64) + partial Ksum per (n,h,chunk) ----------------
// R8 lesson: 1 block/CU = 2 waves/SIMD cannot hide latency regardless of
// ILP depth (VGPR wall at 128). This round: block = (n,h,ck), 8 waves
// s-slice the chunk, in-block LDS tree-reduce at the end. Grid 512 blocks
// -> 2 blocks/CU -> 4 waves/SIMD (2x TLP). NC drops 64->16 -> pKV partial
// traffic 32->8 MB. Pipeline depth 2 (named buffers) keeps VGPR ~114 under
// the launch_bounds(512,4) cap of 128.
#define ROW_LOAD(B, sidx) do {                                   \
    const float* kr_ = Kp + (size_t)(sidx) * (NH * DIM);         \
    const float* vr_ = Vp + (size_t)(sidx) * (NH * DIM);         \
    B##ka = *(const float4*)(kr_ + d0);                          \
    B##kb = *(const float4*)(kr_ + d0 + 4);                      \
    B##va = *(const float4*)(vr_ + v0);                          \
    B##vb = *(const float4*)(vr_ + v0 + 4);                      \
} while (0)

#define ROW_COMPUTE(B) do {                                               \
    float a_[8] = {elu1(B##ka.x), elu1(B##ka.y), elu1(B##ka.z),           \
                   elu1(B##ka.w), elu1(B##kb.x), elu1(B##kb.y),           \
                   elu1(B##kb.z), elu1(B##kb.w)};                         \
    float b_[8] = {B##va.x, B##va.y, B##va.z, B##va.w,                    \
                   B##vb.x, B##vb.y, B##vb.z, B##vb.w};                   \
    _Pragma("unroll")                                                     \
    for (int i_ = 0; i_ < 8; i_++) ks[i_] += a_[i_];                      \
    _Pragma("unroll")                                                     \
    for (int i_ = 0; i_ < 8; i_++)                                        \
        _Pragma("unroll")                                                 \
        for (int j_ = 0; j_ < 8; j_++)                                    \
            acc[i_][j_] = fmaf(a_[i_], b_[j_], acc[i_][j_]);              \
} while (0)

#define ACC_WRITE(BUF, KBUF) do {                                         \
    _Pragma("unroll")                                                     \
    for (int i_ = 0; i_ < 8; i_++)                                        \
        _Pragma("unroll")                                                 \
        for (int j_ = 0; j_ < 8; j_++)                                    \
            BUF[(i_ * 8 + j_) * 64 + lane] = acc[i_][j_];                 \
    if ((lane & 7) == 0) {                                                \
        _Pragma("unroll")                                                 \
        for (int i_ = 0; i_ < 8; i_++) KBUF[d0 + i_] = ks[i_];            \
    }                                                                     \
} while (0)

#define ACC_ADD(BUF, KBUF) do {                                           \
    _Pragma("unroll")                                                     \
    for (int i_ = 0; i_ < 8; i_++)                                        \
        _Pragma("unroll")                                                 \
        for (int j_ = 0; j_ < 8; j_++)                                    \
            acc[i_][j_] += BUF[(i_ * 8 + j_) * 64 + lane];                \
    if ((lane & 7) == 0) {                                                \
        _Pragma("unroll")                                                 \
        for (int i_ = 0; i_ < 8; i_++) ks[i_] += KBUF[d0 + i_];           \
    }                                                                     \
} while (0)

__global__ __launch_bounds__(512, 4) void k_phase1(const float* __restrict__ Kin,
                                                   const float* __restrict__ Vin,
                                                   float* __restrict__ pKV,
                                                   float* __restrict__ pKs,
                                                   int NC, int sLen) {
    const int bx  = blockIdx.x;
    const int n   = bx / (NH * NC);
    const int rem = bx % (NH * NC);
    const int h   = rem / NC;
    const int ck  = rem % NC;
    const int t   = threadIdx.x;
    const int wv   = t >> 6;        // s-slice 0..7
    const int lane = t & 63;
    const int d0 = (lane >> 3) * 8; // owned d block (8)
    const int v0 = (lane & 7) * 8;  // owned v block (8)

    __shared__ __align__(16) float sredA[4096];  // 16 KB
    __shared__ __align__(16) float sredB[4096];  // 16 KB
    __shared__ float ksA[64], ksB[64];

    float acc[8][8];
#pragma unroll
    for (int i = 0; i < 8; i++)
#pragma unroll
        for (int j = 0; j < 8; j++) acc[i][j] = 0.0f;
    float ks[8] = {0.f, 0.f, 0.f, 0.f, 0.f, 0.f, 0.f, 0.f};

    const int rowsPerWave = sLen >> 3;               // 32 at NC=16 (even)
    const int sw = ck * sLen + wv * rowsPerWave;
    const float* Kp = Kin + ((size_t)(n * SEQ + sw) * NH + h) * DIM;
    const float* Vp = Vin + ((size_t)(n * SEQ + sw) * NH + h) * DIM;

    float4 p0ka, p0kb, p0va, p0vb;
    float4 p1ka, p1kb, p1va, p1vb;

    ROW_LOAD(p0, 0);
    ROW_LOAD(p1, 1);
    for (int s = 0; s + 2 < rowsPerWave; s += 2) {
        ROW_COMPUTE(p0); ROW_LOAD(p0, s + 2);
        ROW_COMPUTE(p1); ROW_LOAD(p1, s + 3);
    }
    ROW_COMPUTE(p0);
    ROW_COMPUTE(p1);

    // in-block tree reduce 8 waves -> wave 0 (2 LDS slots, layout
    // elem*64+lane: bank = lane%32, 2 lanes/bank = free)
    if (wv == 1) ACC_WRITE(sredA, ksA);
    if (wv == 5) ACC_WRITE(sredB, ksB);
    __syncthreads();
    if (wv == 0) ACC_ADD(sredA, ksA);
    if (wv == 4) ACC_ADD(sredB, ksB);
    __syncthreads();
    if (wv == 3) ACC_WRITE(sredA, ksA);
    if (wv == 7) ACC_WRITE(sredB, ksB);
    __syncthreads();
    if (wv == 2) ACC_ADD(sredA, ksA);
    if (wv == 6) ACC_ADD(sredB, ksB);
    __syncthreads();
    if (wv == 2) ACC_WRITE(sredA, ksA);
    if (wv == 6) ACC_WRITE(sredB, ksB);
    __syncthreads();
    if (wv == 0) ACC_ADD(sredA, ksA);
    if (wv == 4) ACC_ADD(sredB, ksB);
    __syncthreads();
    if (wv == 4) ACC_WRITE(sredA, ksA);
    __syncthreads();
    if (wv == 0) {
        ACC_ADD(sredA, ksA);
        // store partial KV: pKV[(ck*32 + n*8+h)][d][v]
        const int nh = n * 8 + h;
        float* dst = pKV + ((size_t)ck * 32 + nh) * 4096;
#pragma unroll
        for (int i = 0; i < 8; i++) {
            float4 oa, ob;
            oa.x = acc[i][0]; oa.y = acc[i][1]; oa.z = acc[i][2]; oa.w = acc[i][3];
            ob.x = acc[i][4]; ob.y = acc[i][5]; ob.z = acc[i][6]; ob.w = acc[i][7];
            *(float4*)(dst + (d0 + i) * 64 + v0)     = oa;
            *(float4*)(dst + (d0 + i) * 64 + v0 + 4) = ob;
        }
        if ((lane & 7) == 0) {
#pragma unroll
            for (int i = 0; i < 8; i++)
                pKs[((size_t)ck * 32 + nh) * 64 + d0 + i] = ks[i];
        }
    }
}

// ---------------- Reduce partials -> final KV, Ksum ----------------
template <int NC>
__global__ __launch_bounds__(128) void k_reduceT(const float* __restrict__ pKV,
                                                 const float* __restrict__ pKs,
                                                 float* __restrict__ KVf,
                                                 float* __restrict__ Ksf) {
    const int gid = blockIdx.x * 128 + threadIdx.x;   // 0..32767, one float4 each
    const float4* p4 = (const float4*)pKV;
    float4 s = make_float4(0.f, 0.f, 0.f, 0.f);
#pragma unroll
    for (int c = 0; c < NC; ++c) {
        float4 v = p4[(size_t)c * 32768 + gid];
        s.x += v.x; s.y += v.y; s.z += v.z; s.w += v.w;
    }
    ((float4*)KVf)[gid] = s;
    if (gid < 2048) {
        float ss = 0.0f;
#pragma unroll
        for (int c = 0; c < NC; ++c) ss += pKs[(size_t)c * 2048 + gid];
        Ksf[gid] = ss;
    }
}

__global__ __launch_bounds__(128) void k_reduceG(const float* __restrict__ pKV,
                                                 const float* __restrict__ pKs,
                                                 float* __restrict__ KVf,
                                                 float* __restrict__ Ksf, int NC) {
    const int gid = blockIdx.x * 128 + threadIdx.x;
    const float4* p4 = (const float4*)pKV;
    float4 s = make_float4(0.f, 0.f, 0.f, 0.f);
    for (int c = 0; c < NC; ++c) {
        float4 v = p4[(size_t)c * 32768 + gid];
        s.x += v.x; s.y += v.y; s.z += v.z; s.w += v.w;
    }
    ((float4*)KVf)[gid] = s;
    if (gid < 2048) {
        float ss = 0.0f;
        for (int c = 0; c < NC; ++c) ss += pKs[(size_t)c * 2048 + gid];
        Ksf[gid] = ss;
    }
}

// ---------------- Phase 2: register-tiled GEMM, out[l,v] = (Qf.KV[:,v]) / (Qf.Ks + eps) ----------------
// (R4/R5-benched version, ~14.5us: 512 blocks, 8x8 per-thread tile, Qt chunked
// to 16 d-rows, swizzle col = row ^ (dl&12) -> <=2-way on writes and reads.)
__global__ __launch_bounds__(256) void k_phase2(const float* __restrict__ Qin,
                                                const float* __restrict__ KVf,
                                                const float* __restrict__ Ksf,
                                                float* __restrict__ Out) {
    const int nh   = blockIdx.x >> 4;
    const int tile = blockIdx.x & 15;
    const int n = nh >> 3, h = nh & 7;
    const int t = threadIdx.x;

    __shared__ __align__(16) float Qt[16 * 256];   // 16 KB, swizzled transpose chunk
    __shared__ __align__(16) float KVs[64][64];    // 16 KB
    __shared__ float Kss[64];

    // stage KV + Ksum (coalesced; small, L2/L3-resident)
    {
        const float4* src = (const float4*)(KVf + (size_t)nh * 4096);
        float4* dst = (float4*)&KVs[0][0];
#pragma unroll
        for (int i = 0; i < 4; ++i) dst[t + 256 * i] = src[t + 256 * i];
        if (t < 64) Kss[t] = Ksf[nh * 64 + t];
    }

    const int l0 = tile * 256;
    const int r0 = (t >> 3) * 8;     // owned rows (8), 0..248
    const int v0 = (t & 7) * 8;      // owned cols (8)

    float acc[8][8];
#pragma unroll
    for (int i = 0; i < 8; i++)
#pragma unroll
        for (int j = 0; j < 8; j++) acc[i][j] = 0.0f;
    float p[8] = {0.f, 0.f, 0.f, 0.f, 0.f, 0.f, 0.f, 0.f};

    for (int dc = 0; dc < 4; ++dc) {
        if (dc) __syncthreads();       // protect Qt before overwrite
        // stage Q chunk (16 d) transposed+swizzled: 1024 float4
#pragma unroll
        for (int i = 0; i < 4; ++i) {
            const int j   = t + 256 * i;
            const int row = j >> 2;           // 0..255
            const int dl4 = (j & 3) << 2;     // local d f4-group: 0,4,8,12
            const size_t g = ((size_t)(n * SEQ + l0 + row) * NH + h) * DIM + dc * 16 + dl4;
            float4 q4 = *(const float4*)(Qin + g);
            const int col = row ^ dl4;
            Qt[(dl4 + 0) * 256 + col] = elu1(q4.x);
            Qt[(dl4 + 1) * 256 + col] = elu1(q4.y);
            Qt[(dl4 + 2) * 256 + col] = elu1(q4.z);
            Qt[(dl4 + 3) * 256 + col] = elu1(q4.w);
        }
        __syncthreads();

#pragma unroll 2
        for (int dl = 0; dl < 16; ++dl) {
            const int d = dc * 16 + dl;
            const int s = dl & 12;
            float4 qa = *(const float4*)&Qt[dl * 256 + (r0 ^ s)];
            float4 qb = *(const float4*)&Qt[dl * 256 + ((r0 + 4) ^ s)];
            float4 ka = *(const float4*)&KVs[d][v0];
            float4 kb = *(const float4*)&KVs[d][v0 + 4];
            const float ksd = Kss[d];
            float q[8]  = {qa.x, qa.y, qa.z, qa.w, qb.x, qb.y, qb.z, qb.w};
            float kv[8] = {ka.x, ka.y, ka.z, ka.w, kb.x, kb.y, kb.z, kb.w};
#pragma unroll
            for (int i = 0; i < 8; ++i) {
                p[i] = fmaf(q[i], ksd, p[i]);
#pragma unroll
                for (int jj = 0; jj < 8; ++jj)
                    acc[i][jj] = fmaf(q[i], kv[jj], acc[i][jj]);
            }
        }
    }

    // epilogue: scale by 1/(p+eps), float4 stores
#pragma unroll
    for (int i = 0; i < 8; ++i) {
        const float z = 1.0f / (p[i] + 1e-6f);
        const int l = l0 + r0 + i;
        float* o = Out + ((size_t)(n * SEQ + l) * NH + h) * DIM + v0;
        float4 oa, ob;
        oa.x = acc[i][0] * z; oa.y = acc[i][1] * z; oa.z = acc[i][2] * z; oa.w = acc[i][3] * z;
        ob.x = acc[i][4] * z; ob.y = acc[i][5] * z; ob.z = acc[i][6] * z; ob.w = acc[i][7] * z;
        *(float4*)(o)     = oa;
        *(float4*)(o + 4) = ob;
    }
}

extern "C" void kernel_launch(void* const* d_in, const int* in_sizes, int n_in,
                              void* d_out, int out_size, void* d_ws, size_t ws_size,
                              hipStream_t stream) {
    const float* Q = (const float*)d_in[0];
    const float* K = (const float*)d_in[1];
    const float* V = (const float*)d_in[2];
    float* out = (float*)d_out;

    // ws layout: [KVf 32*4096][Ksf 32*64][pKV NC*32*4096][pKs NC*32*64]
    int NC = 16;  // grid = 32*NC = 512 blocks of 512 thr -> 2 blocks/CU
    const size_t unit = 133120ull * 4ull; // (4096+64)*32 floats in bytes
    while (NC > 1 && (size_t)(NC + 1) * unit > ws_size) NC >>= 1;
    const int sLen = SEQ / NC;

    float* KVf = (float*)d_ws;
    float* Ksf = KVf + 32 * 4096;
    float* pKV = Ksf + 32 * 64;
    float* pKs = pKV + (size_t)NC * 32 * 4096;

    hipLaunchKernelGGL(k_phase1, dim3(32 * NC), dim3(512), 0, stream, K, V, pKV, pKs, NC, sLen);
    switch (NC) {
        case 16: hipLaunchKernelGGL(k_reduceT<16>, dim3(256), dim3(128), 0, stream, pKV, pKs, KVf, Ksf); break;
        case 8:  hipLaunchKernelGGL(k_reduceT<8>,  dim3(256), dim3(128), 0, stream, pKV, pKs, KVf, Ksf); break;
        case 4:  hipLaunchKernelGGL(k_reduceT<4>,  dim3(256), dim3(128), 0, stream, pKV, pKs, KVf, Ksf); break;
        default: hipLaunchKernelGGL(k_reduceG, dim3(256), dim3(128), 0, stream, pKV, pKs, KVf, Ksf, NC); break;
    }
    hipLaunchKernelGGL(k_phase2, dim3(512), dim3(256), 0, stream, Q, KVf, Ksf, out);
}

// Round 10
// 88.616 us; speedup vs baseline: 3.4109x; 3.4109x over previous
//
#include <hip/hip_runtime.h>
#include <math.h>

#define SEQ 4096
#define NH  8
#define DIM 64
// 32 (n,h) pairs total: n=4, h=8

__device__ __forceinline__ float elu1(float x) {
    // jax.nn.elu(x)+1: branchless — exp(min(x,0)) + max(x,0)
    return __expf(fminf(x, 0.0f)) + fmaxf(x, 0.0f);
}

// ---------------- Phase 1: partial KV (64x64) + partial Ksum per (n,h,chunk) ----------------
// R9 lesson: launch_bounds min-waves cap + ~115 live regs = scratch spills
// (VGPR forced to 64, FETCH 298MB). R8 lesson: 256-block grid = 1 block/CU =
// 2 waves/SIMD, grid-limited TLP.
// This round: block = (n, head-quad, ck): 8 waves = 4 heads x 2 s-slices.
// Reads stay contiguous (4x256B segments per s, R7-proven clean FETCH);
// grid = 4n*2hq*NC = 512 blocks -> 2 blocks/CU -> 4 waves/SIMD, PROVIDED
// VGPR <= 128 — so NO min-waves cap, dist-2 pipeline only (~115 regs).
// Pair-waves (w, w+4) share (head, chunk): tree-reduce via 2x16KB LDS slots.
#define ROW_LOAD(B, sidx) do {                                   \
    const float* kr_ = Kp + (size_t)(sidx) * (NH * DIM);         \
    const float* vr_ = Vp + (size_t)(sidx) * (NH * DIM);         \
    B##ka = *(const float4*)(kr_ + d0);                          \
    B##kb = *(const float4*)(kr_ + d0 + 4);                      \
    B##va = *(const float4*)(vr_ + v0);                          \
    B##vb = *(const float4*)(vr_ + v0 + 4);                      \
} while (0)

#define ROW_COMPUTE(B) do {                                               \
    float a_[8] = {elu1(B##ka.x), elu1(B##ka.y), elu1(B##ka.z),           \
                   elu1(B##ka.w), elu1(B##kb.x), elu1(B##kb.y),           \
                   elu1(B##kb.z), elu1(B##kb.w)};                         \
    float b_[8] = {B##va.x, B##va.y, B##va.z, B##va.w,                    \
                   B##vb.x, B##vb.y, B##vb.z, B##vb.w};                   \
    _Pragma("unroll")                                                     \
    for (int i_ = 0; i_ < 8; i_++) ks[i_] += a_[i_];                      \
    _Pragma("unroll")                                                     \
    for (int i_ = 0; i_ < 8; i_++)                                        \
        _Pragma("unroll")                                                 \
        for (int j_ = 0; j_ < 8; j_++)                                    \
            acc[i_][j_] = fmaf(a_[i_], b_[j_], acc[i_][j_]);              \
} while (0)

#define ACC_WRITE(BUF, KBUF) do {                                         \
    _Pragma("unroll")                                                     \
    for (int i_ = 0; i_ < 8; i_++)                                        \
        _Pragma("unroll")                                                 \
        for (int j_ = 0; j_ < 8; j_++)                                    \
            BUF[(i_ * 8 + j_) * 64 + lane] = acc[i_][j_];                 \
    if ((lane & 7) == 0) {                                                \
        _Pragma("unroll")                                                 \
        for (int i_ = 0; i_ < 8; i_++) KBUF[d0 + i_] = ks[i_];            \
    }                                                                     \
} while (0)

#define ACC_ADD(BUF, KBUF) do {                                           \
    _Pragma("unroll")                                                     \
    for (int i_ = 0; i_ < 8; i_++)                                        \
        _Pragma("unroll")                                                 \
        for (int j_ = 0; j_ < 8; j_++)                                    \
            acc[i_][j_] += BUF[(i_ * 8 + j_) * 64 + lane];                \
    if ((lane & 7) == 0) {                                                \
        _Pragma("unroll")                                                 \
        for (int i_ = 0; i_ < 8; i_++) ks[i_] += KBUF[d0 + i_];           \
    }                                                                     \
} while (0)

__global__ __launch_bounds__(512) void k_phase1(const float* __restrict__ Kin,
                                                const float* __restrict__ Vin,
                                                float* __restrict__ pKV,
                                                float* __restrict__ pKs,
                                                int NC, int sLen) {
    const int bx  = blockIdx.x;
    const int n   = bx / (2 * NC);
    const int rem = bx % (2 * NC);
    const int hq  = rem / NC;       // head quad 0..1
    const int ck  = rem % NC;
    const int t   = threadIdx.x;
    const int wv    = t >> 6;       // 0..7
    const int lane  = t & 63;
    const int h     = hq * 4 + (wv & 3);
    const int shalf = wv >> 2;      // s-slice 0..1
    const int d0 = (lane >> 3) * 8; // owned d block (8)
    const int v0 = (lane & 7) * 8;  // owned v block (8)

    __shared__ __align__(16) float sredA[4096];  // 16 KB
    __shared__ __align__(16) float sredB[4096];  // 16 KB
    __shared__ float ksA[64], ksB[64];

    float acc[8][8];
#pragma unroll
    for (int i = 0; i < 8; i++)
#pragma unroll
        for (int j = 0; j < 8; j++) acc[i][j] = 0.0f;
    float ks[8] = {0.f, 0.f, 0.f, 0.f, 0.f, 0.f, 0.f, 0.f};

    const int rowsPerWave = sLen >> 1;              // 32 at NC=64
    const int sw = ck * sLen + shalf * rowsPerWave;
    const float* Kp = Kin + ((size_t)(n * SEQ + sw) * NH + h) * DIM;
    const float* Vp = Vin + ((size_t)(n * SEQ + sw) * NH + h) * DIM;

    float4 p0ka, p0kb, p0va, p0vb;
    float4 p1ka, p1kb, p1va, p1vb;

    ROW_LOAD(p0, 0);
    ROW_LOAD(p1, 1);
    for (int s = 0; s + 2 < rowsPerWave; s += 2) {
        ROW_COMPUTE(p0); ROW_LOAD(p0, s + 2);
        ROW_COMPUTE(p1); ROW_LOAD(p1, s + 3);
    }
    ROW_COMPUTE(p0);
    ROW_COMPUTE(p1);

    // pair reduce (w+4 -> w) in two rounds through 2 slots
    if (wv == 4) ACC_WRITE(sredA, ksA);
    if (wv == 5) ACC_WRITE(sredB, ksB);
    __syncthreads();
    if (wv == 0) ACC_ADD(sredA, ksA);
    if (wv == 1) ACC_ADD(sredB, ksB);
    __syncthreads();
    if (wv == 6) ACC_WRITE(sredA, ksA);
    if (wv == 7) ACC_WRITE(sredB, ksB);
    __syncthreads();
    if (wv == 2) ACC_ADD(sredA, ksA);
    if (wv == 3) ACC_ADD(sredB, ksB);

    // waves 0..3 store their head's partial: pKV[(ck*32 + n*8+h)][d][v]
    if (wv < 4) {
        const int nh = n * 8 + h;
        float* dst = pKV + ((size_t)ck * 32 + nh) * 4096;
#pragma unroll
        for (int i = 0; i < 8; i++) {
            float4 oa, ob;
            oa.x = acc[i][0]; oa.y = acc[i][1]; oa.z = acc[i][2]; oa.w = acc[i][3];
            ob.x = acc[i][4]; ob.y = acc[i][5]; ob.z = acc[i][6]; ob.w = acc[i][7];
            *(float4*)(dst + (d0 + i) * 64 + v0)     = oa;
            *(float4*)(dst + (d0 + i) * 64 + v0 + 4) = ob;
        }
        if ((lane & 7) == 0) {
#pragma unroll
            for (int i = 0; i < 8; i++)
                pKs[((size_t)ck * 32 + nh) * 64 + d0 + i] = ks[i];
        }
    }
}

// ---------------- Reduce partials -> final KV, Ksum ----------------
template <int NC>
__global__ __launch_bounds__(128) void k_reduceT(const float* __restrict__ pKV,
                                                 const float* __restrict__ pKs,
                                                 float* __restrict__ KVf,
                                                 float* __restrict__ Ksf) {
    const int gid = blockIdx.x * 128 + threadIdx.x;   // 0..32767, one float4 each
    const float4* p4 = (const float4*)pKV;
    float4 s = make_float4(0.f, 0.f, 0.f, 0.f);
#pragma unroll
    for (int c = 0; c < NC; ++c) {
        float4 v = p4[(size_t)c * 32768 + gid];
        s.x += v.x; s.y += v.y; s.z += v.z; s.w += v.w;
    }
    ((float4*)KVf)[gid] = s;
    if (gid < 2048) {
        float ss = 0.0f;
#pragma unroll
        for (int c = 0; c < NC; ++c) ss += pKs[(size_t)c * 2048 + gid];
        Ksf[gid] = ss;
    }
}

__global__ __launch_bounds__(128) void k_reduceG(const float* __restrict__ pKV,
                                                 const float* __restrict__ pKs,
                                                 float* __restrict__ KVf,
                                                 float* __restrict__ Ksf, int NC) {
    const int gid = blockIdx.x * 128 + threadIdx.x;
    const float4* p4 = (const float4*)pKV;
    float4 s = make_float4(0.f, 0.f, 0.f, 0.f);
    for (int c = 0; c < NC; ++c) {
        float4 v = p4[(size_t)c * 32768 + gid];
        s.x += v.x; s.y += v.y; s.z += v.z; s.w += v.w;
    }
    ((float4*)KVf)[gid] = s;
    if (gid < 2048) {
        float ss = 0.0f;
        for (int c = 0; c < NC; ++c) ss += pKs[(size_t)c * 2048 + gid];
        Ksf[gid] = ss;
    }
}

// ---------------- Phase 2: register-tiled GEMM, out[l,v] = (Qf.KV[:,v]) / (Qf.Ks + eps) ----------------
// (R4/R5-benched version, ~14.5us: 512 blocks, 8x8 per-thread tile, Qt chunked
// to 16 d-rows, swizzle col = row ^ (dl&12) -> <=2-way on writes and reads.)
__global__ __launch_bounds__(256) void k_phase2(const float* __restrict__ Qin,
                                                const float* __restrict__ KVf,
                                                const float* __restrict__ Ksf,
                                                float* __restrict__ Out) {
    const int nh   = blockIdx.x >> 4;
    const int tile = blockIdx.x & 15;
    const int n = nh >> 3, h = nh & 7;
    const int t = threadIdx.x;

    __shared__ __align__(16) float Qt[16 * 256];   // 16 KB, swizzled transpose chunk
    __shared__ __align__(16) float KVs[64][64];    // 16 KB
    __shared__ float Kss[64];

    // stage KV + Ksum (coalesced; small, L2/L3-resident)
    {
        const float4* src = (const float4*)(KVf + (size_t)nh * 4096);
        float4* dst = (float4*)&KVs[0][0];
#pragma unroll
        for (int i = 0; i < 4; ++i) dst[t + 256 * i] = src[t + 256 * i];
        if (t < 64) Kss[t] = Ksf[nh * 64 + t];
    }

    const int l0 = tile * 256;
    const int r0 = (t >> 3) * 8;     // owned rows (8), 0..248
    const int v0 = (t & 7) * 8;      // owned cols (8)

    float acc[8][8];
#pragma unroll
    for (int i = 0; i < 8; i++)
#pragma unroll
        for (int j = 0; j < 8; j++) acc[i][j] = 0.0f;
    float p[8] = {0.f, 0.f, 0.f, 0.f, 0.f, 0.f, 0.f, 0.f};

    for (int dc = 0; dc < 4; ++dc) {
        if (dc) __syncthreads();       // protect Qt before overwrite
        // stage Q chunk (16 d) transposed+swizzled: 1024 float4
#pragma unroll
        for (int i = 0; i < 4; ++i) {
            const int j   = t + 256 * i;
            const int row = j >> 2;           // 0..255
            const int dl4 = (j & 3) << 2;     // local d f4-group: 0,4,8,12
            const size_t g = ((size_t)(n * SEQ + l0 + row) * NH + h) * DIM + dc * 16 + dl4;
            float4 q4 = *(const float4*)(Qin + g);
            const int col = row ^ dl4;
            Qt[(dl4 + 0) * 256 + col] = elu1(q4.x);
            Qt[(dl4 + 1) * 256 + col] = elu1(q4.y);
            Qt[(dl4 + 2) * 256 + col] = elu1(q4.z);
            Qt[(dl4 + 3) * 256 + col] = elu1(q4.w);
        }
        __syncthreads();

#pragma unroll 2
        for (int dl = 0; dl < 16; ++dl) {
            const int d = dc * 16 + dl;
            const int s = dl & 12;
            float4 qa = *(const float4*)&Qt[dl * 256 + (r0 ^ s)];
            float4 qb = *(const float4*)&Qt[dl * 256 + ((r0 + 4) ^ s)];
            float4 ka = *(const float4*)&KVs[d][v0];
            float4 kb = *(const float4*)&KVs[d][v0 + 4];
            const float ksd = Kss[d];
            float q[8]  = {qa.x, qa.y, qa.z, qa.w, qb.x, qb.y, qb.z, qb.w};
            float kv[8] = {ka.x, ka.y, ka.z, ka.w, kb.x, kb.y, kb.z, kb.w};
#pragma unroll
            for (int i = 0; i < 8; ++i) {
                p[i] = fmaf(q[i], ksd, p[i]);
#pragma unroll
                for (int jj = 0; jj < 8; ++jj)
                    acc[i][jj] = fmaf(q[i], kv[jj], acc[i][jj]);
            }
        }
    }

    // epilogue: scale by 1/(p+eps), float4 stores
#pragma unroll
    for (int i = 0; i < 8; ++i) {
        const float z = 1.0f / (p[i] + 1e-6f);
        const int l = l0 + r0 + i;
        float* o = Out + ((size_t)(n * SEQ + l) * NH + h) * DIM + v0;
        float4 oa, ob;
        oa.x = acc[i][0] * z; oa.y = acc[i][1] * z; oa.z = acc[i][2] * z; oa.w = acc[i][3] * z;
        ob.x = acc[i][4] * z; ob.y = acc[i][5] * z; ob.z = acc[i][6] * z; ob.w = acc[i][7] * z;
        *(float4*)(o)     = oa;
        *(float4*)(o + 4) = ob;
    }
}

extern "C" void kernel_launch(void* const* d_in, const int* in_sizes, int n_in,
                              void* d_out, int out_size, void* d_ws, size_t ws_size,
                              hipStream_t stream) {
    const float* Q = (const float*)d_in[0];
    const float* K = (const float*)d_in[1];
    const float* V = (const float*)d_in[2];
    float* out = (float*)d_out;

    // ws layout: [KVf 32*4096][Ksf 32*64][pKV NC*32*4096][pKs NC*32*64]
    int NC = 64;  // grid = 8*NC = 512 blocks of 512 thr -> 2 blocks/CU
    const size_t unit = 133120ull * 4ull; // (4096+64)*32 floats in bytes
    while (NC > 1 && (size_t)(NC + 1) * unit > ws_size) NC >>= 1;
    const int sLen = SEQ / NC;

    float* KVf = (float*)d_ws;
    float* Ksf = KVf + 32 * 4096;
    float* pKV = Ksf + 32 * 64;
    float* pKs = pKV + (size_t)NC * 32 * 4096;

    hipLaunchKernelGGL(k_phase1, dim3(8 * NC), dim3(512), 0, stream, K, V, pKV, pKs, NC, sLen);
    switch (NC) {
        case 64: hipLaunchKernelGGL(k_reduceT<64>, dim3(256), dim3(128), 0, stream, pKV, pKs, KVf, Ksf); break;
        case 32: hipLaunchKernelGGL(k_reduceT<32>, dim3(256), dim3(128), 0, stream, pKV, pKs, KVf, Ksf); break;
        case 16: hipLaunchKernelGGL(k_reduceT<16>, dim3(256), dim3(128), 0, stream, pKV, pKs, KVf, Ksf); break;
        case 8:  hipLaunchKernelGGL(k_reduceT<8>,  dim3(256), dim3(128), 0, stream, pKV, pKs, KVf, Ksf); break;
        default: hipLaunchKernelGGL(k_reduceG, dim3(256), dim3(128), 0, stream, pKV, pKs, KVf, Ksf, NC); break;
    }
    hipLaunchKernelGGL(k_phase2, dim3(512), dim3(256), 0, stream, Q, KVf, Ksf, out);
}

// Round 11
// 56.408 us; speedup vs baseline: 5.3585x; 1.5710x over previous
//
#include <hip/hip_runtime.h>
#include <math.h>

#define SEQ 4096
#define NH  8
#define DIM 64
// 32 (n,h) pairs total: n=4, h=8

__device__ __forceinline__ float elu1(float x) {
    // jax.nn.elu(x)+1: branchless — exp(min(x,0)) + max(x,0)
    return __expf(fminf(x, 0.0f)) + fmaxf(x, 0.0f);
}

// ---------------- Phase 1: partial KV (64x64) + partial Ksum per (n,h,chunk) ----------------
// R7/R8/R10 all pinned at ~50us: reg-direct strided-segment streaming is
// latency-capped regardless of ILP/TLP knobs. This round copies the PROVEN
// phase2 shape (14.5us @ 4.6TB/s): 64-row LDS tile (32KB: elu'd K + V),
// 8 float4 loads/thread issued together per stage, barrier, 1024 fma/thread
// (~2048 cyc) per tile — 4x the compute per exposed stage latency of R5.
// 4 waves s-split the tile; block = (n,h,ck), NC=16 -> 512 blocks, 2/CU.
// Acc tree-reduce ONCE per block through the kf/vv LDS (reused, no extra).
__global__ __launch_bounds__(256) void k_phase1(const float* __restrict__ Kin,
                                                const float* __restrict__ Vin,
                                                float* __restrict__ pKV,
                                                float* __restrict__ pKs,
                                                int NC, int sLen) {
    const int nh = blockIdx.x / NC;
    const int ck = blockIdx.x % NC;
    const int n  = nh >> 3, h = nh & 7;
    const int t  = threadIdx.x;
    const int r  = t >> 4;            // staging row 0..15
    const int c4 = (t & 15) * 4;      // staging col x4
    const int wv = t >> 6, lane = t & 63;
    const int d0 = (lane >> 3) * 8;   // owned d block (8)
    const int v0 = (lane & 7) * 8;    // owned v block (8)

    __shared__ __align__(16) float kf[4096];   // 16 KB: elu'd K tile [64][64]; reused as acc-reduce slot A
    __shared__ __align__(16) float vv[4096];   // 16 KB: V tile [64][64]; reused as slot B + ksum reduce

    float acc[8][8];
#pragma unroll
    for (int i = 0; i < 8; i++)
#pragma unroll
        for (int j = 0; j < 8; j++) acc[i][j] = 0.0f;
    float ksl[4] = {0.f, 0.f, 0.f, 0.f};

    const size_t base = ((size_t)(n * SEQ + ck * sLen) * NH + h) * DIM;
    const int ntiles = sLen >> 6;

    for (int tile = 0; tile < ntiles; ++tile) {
        if (tile) __syncthreads();               // prior compute done; LDS reusable
        // ---- stage 64 rows: 8 float4 loads issued together, then elu+write ----
        const float* Kb = Kin + base + ((size_t)tile * 64 + r) * (NH * DIM) + c4;
        const float* Vb = Vin + base + ((size_t)tile * 64 + r) * (NH * DIM) + c4;
        float4 kreg[4], vreg[4];
#pragma unroll
        for (int i = 0; i < 4; ++i) {
            kreg[i] = *(const float4*)(Kb + (size_t)i * 16 * (NH * DIM));
            vreg[i] = *(const float4*)(Vb + (size_t)i * 16 * (NH * DIM));
        }
#pragma unroll
        for (int i = 0; i < 4; ++i) {
            float4 f4;
            f4.x = elu1(kreg[i].x); f4.y = elu1(kreg[i].y);
            f4.z = elu1(kreg[i].z); f4.w = elu1(kreg[i].w);
            ksl[0] += f4.x; ksl[1] += f4.y; ksl[2] += f4.z; ksl[3] += f4.w;
            *(float4*)&kf[(r + 16 * i) * 64 + c4] = f4;
            *(float4*)&vv[(r + 16 * i) * 64 + c4] = vreg[i];
        }
        __syncthreads();
        // ---- compute: each wave its 16 s-rows, 64 fma each (broadcast LDS reads are cheap) ----
#pragma unroll 2
        for (int ssi = 0; ssi < 16; ++ssi) {
            const int ss = wv * 16 + ssi;
            float4 a0 = *(const float4*)&kf[ss * 64 + d0];
            float4 a1 = *(const float4*)&kf[ss * 64 + d0 + 4];
            float4 b0 = *(const float4*)&vv[ss * 64 + v0];
            float4 b1 = *(const float4*)&vv[ss * 64 + v0 + 4];
            float a[8] = {a0.x, a0.y, a0.z, a0.w, a1.x, a1.y, a1.z, a1.w};
            float b[8] = {b0.x, b0.y, b0.z, b0.w, b1.x, b1.y, b1.z, b1.w};
#pragma unroll
            for (int i = 0; i < 8; i++)
#pragma unroll
                for (int j = 0; j < 8; j++)
                    acc[i][j] = fmaf(a[i], b[j], acc[i][j]);
        }
    }
    __syncthreads();    // all compute done; kf/vv free for reduction

    // ---- acc tree-reduce 4 waves -> wave 0 (slots: kf, vv; layout elem*64+lane) ----
#define ACC_W(S) { _Pragma("unroll") for (int i_=0;i_<8;i_++) _Pragma("unroll") for (int j_=0;j_<8;j_++) (S)[(i_*8+j_)*64+lane]=acc[i_][j_]; }
#define ACC_A(S) { _Pragma("unroll") for (int i_=0;i_<8;i_++) _Pragma("unroll") for (int j_=0;j_<8;j_++) acc[i_][j_]+=(S)[(i_*8+j_)*64+lane]; }
    if (wv == 1) ACC_W(kf);
    if (wv == 3) ACC_W(vv);
    __syncthreads();
    if (wv == 0) ACC_A(kf);
    if (wv == 2) ACC_A(vv);
    __syncthreads();
    if (wv == 2) ACC_W(kf);
    __syncthreads();
    if (wv == 0) {
        ACC_A(kf);
        const int pnh = n * 8 + h;
        float* dst = pKV + ((size_t)ck * 32 + pnh) * 4096;
#pragma unroll
        for (int i = 0; i < 8; i++) {
            float4 oa, ob;
            oa.x = acc[i][0]; oa.y = acc[i][1]; oa.z = acc[i][2]; oa.w = acc[i][3];
            ob.x = acc[i][4]; ob.y = acc[i][5]; ob.z = acc[i][6]; ob.w = acc[i][7];
            *(float4*)(dst + (d0 + i) * 64 + v0)     = oa;
            *(float4*)(dst + (d0 + i) * 64 + v0 + 4) = ob;
        }
    }
    // ---- ksum reduce via vv (free: last read before the w2->kf barrier) ----
    *(float4*)&vv[r * 64 + c4] = make_float4(ksl[0], ksl[1], ksl[2], ksl[3]);
    __syncthreads();
    if (t < 64) {
        float s = 0.0f;
#pragma unroll
        for (int rr = 0; rr < 16; ++rr) s += vv[rr * 64 + t];
        pKs[((size_t)ck * 32 + n * 8 + h) * 64 + t] = s;
    }
}

// ---------------- Reduce partials -> final KV, Ksum ----------------
template <int NC>
__global__ __launch_bounds__(128) void k_reduceT(const float* __restrict__ pKV,
                                                 const float* __restrict__ pKs,
                                                 float* __restrict__ KVf,
                                                 float* __restrict__ Ksf) {
    const int gid = blockIdx.x * 128 + threadIdx.x;   // 0..32767, one float4 each
    const float4* p4 = (const float4*)pKV;
    float4 s = make_float4(0.f, 0.f, 0.f, 0.f);
#pragma unroll
    for (int c = 0; c < NC; ++c) {
        float4 v = p4[(size_t)c * 32768 + gid];
        s.x += v.x; s.y += v.y; s.z += v.z; s.w += v.w;
    }
    ((float4*)KVf)[gid] = s;
    if (gid < 2048) {
        float ss = 0.0f;
#pragma unroll
        for (int c = 0; c < NC; ++c) ss += pKs[(size_t)c * 2048 + gid];
        Ksf[gid] = ss;
    }
}

__global__ __launch_bounds__(128) void k_reduceG(const float* __restrict__ pKV,
                                                 const float* __restrict__ pKs,
                                                 float* __restrict__ KVf,
                                                 float* __restrict__ Ksf, int NC) {
    const int gid = blockIdx.x * 128 + threadIdx.x;
    const float4* p4 = (const float4*)pKV;
    float4 s = make_float4(0.f, 0.f, 0.f, 0.f);
    for (int c = 0; c < NC; ++c) {
        float4 v = p4[(size_t)c * 32768 + gid];
        s.x += v.x; s.y += v.y; s.z += v.z; s.w += v.w;
    }
    ((float4*)KVf)[gid] = s;
    if (gid < 2048) {
        float ss = 0.0f;
        for (int c = 0; c < NC; ++c) ss += pKs[(size_t)c * 2048 + gid];
        Ksf[gid] = ss;
    }
}

// ---------------- Phase 2: register-tiled GEMM, out[l,v] = (Qf.KV[:,v]) / (Qf.Ks + eps) ----------------
// (R4/R5-benched version, ~14.5us: 512 blocks, 8x8 per-thread tile, Qt chunked
// to 16 d-rows, swizzle col = row ^ (dl&12) -> <=2-way on writes and reads.)
__global__ __launch_bounds__(256) void k_phase2(const float* __restrict__ Qin,
                                                const float* __restrict__ KVf,
                                                const float* __restrict__ Ksf,
                                                float* __restrict__ Out) {
    const int nh   = blockIdx.x >> 4;
    const int tile = blockIdx.x & 15;
    const int n = nh >> 3, h = nh & 7;
    const int t = threadIdx.x;

    __shared__ __align__(16) float Qt[16 * 256];   // 16 KB, swizzled transpose chunk
    __shared__ __align__(16) float KVs[64][64];    // 16 KB
    __shared__ float Kss[64];

    // stage KV + Ksum (coalesced; small, L2/L3-resident)
    {
        const float4* src = (const float4*)(KVf + (size_t)nh * 4096);
        float4* dst = (float4*)&KVs[0][0];
#pragma unroll
        for (int i = 0; i < 4; ++i) dst[t + 256 * i] = src[t + 256 * i];
        if (t < 64) Kss[t] = Ksf[nh * 64 + t];
    }

    const int l0 = tile * 256;
    const int r0 = (t >> 3) * 8;     // owned rows (8), 0..248
    const int v0 = (t & 7) * 8;      // owned cols (8)

    float acc[8][8];
#pragma unroll
    for (int i = 0; i < 8; i++)
#pragma unroll
        for (int j = 0; j < 8; j++) acc[i][j] = 0.0f;
    float p[8] = {0.f, 0.f, 0.f, 0.f, 0.f, 0.f, 0.f, 0.f};

    for (int dc = 0; dc < 4; ++dc) {
        if (dc) __syncthreads();       // protect Qt before overwrite
        // stage Q chunk (16 d) transposed+swizzled: 1024 float4
#pragma unroll
        for (int i = 0; i < 4; ++i) {
            const int j   = t + 256 * i;
            const int row = j >> 2;           // 0..255
            const int dl4 = (j & 3) << 2;     // local d f4-group: 0,4,8,12
            const size_t g = ((size_t)(n * SEQ + l0 + row) * NH + h) * DIM + dc * 16 + dl4;
            float4 q4 = *(const float4*)(Qin + g);
            const int col = row ^ dl4;
            Qt[(dl4 + 0) * 256 + col] = elu1(q4.x);
            Qt[(dl4 + 1) * 256 + col] = elu1(q4.y);
            Qt[(dl4 + 2) * 256 + col] = elu1(q4.z);
            Qt[(dl4 + 3) * 256 + col] = elu1(q4.w);
        }
        __syncthreads();

#pragma unroll 2
        for (int dl = 0; dl < 16; ++dl) {
            const int d = dc * 16 + dl;
            const int s = dl & 12;
            float4 qa = *(const float4*)&Qt[dl * 256 + (r0 ^ s)];
            float4 qb = *(const float4*)&Qt[dl * 256 + ((r0 + 4) ^ s)];
            float4 ka = *(const float4*)&KVs[d][v0];
            float4 kb = *(const float4*)&KVs[d][v0 + 4];
            const float ksd = Kss[d];
            float q[8]  = {qa.x, qa.y, qa.z, qa.w, qb.x, qb.y, qb.z, qb.w};
            float kv[8] = {ka.x, ka.y, ka.z, ka.w, kb.x, kb.y, kb.z, kb.w};
#pragma unroll
            for (int i = 0; i < 8; ++i) {
                p[i] = fmaf(q[i], ksd, p[i]);
#pragma unroll
                for (int jj = 0; jj < 8; ++jj)
                    acc[i][jj] = fmaf(q[i], kv[jj], acc[i][jj]);
            }
        }
    }

    // epilogue: scale by 1/(p+eps), float4 stores
#pragma unroll
    for (int i = 0; i < 8; ++i) {
        const float z = 1.0f / (p[i] + 1e-6f);
        const int l = l0 + r0 + i;
        float* o = Out + ((size_t)(n * SEQ + l) * NH + h) * DIM + v0;
        float4 oa, ob;
        oa.x = acc[i][0] * z; oa.y = acc[i][1] * z; oa.z = acc[i][2] * z; oa.w = acc[i][3] * z;
        ob.x = acc[i][4] * z; ob.y = acc[i][5] * z; ob.z = acc[i][6] * z; ob.w = acc[i][7] * z;
        *(float4*)(o)     = oa;
        *(float4*)(o + 4) = ob;
    }
}

extern "C" void kernel_launch(void* const* d_in, const int* in_sizes, int n_in,
                              void* d_out, int out_size, void* d_ws, size_t ws_size,
                              hipStream_t stream) {
    const float* Q = (const float*)d_in[0];
    const float* K = (const float*)d_in[1];
    const float* V = (const float*)d_in[2];
    float* out = (float*)d_out;

    // ws layout: [KVf 32*4096][Ksf 32*64][pKV NC*32*4096][pKs NC*32*64]
    int NC = 16;  // grid = 32*NC = 512 blocks of 256 thr -> 2 blocks/CU
    const size_t unit = 133120ull * 4ull; // (4096+64)*32 floats in bytes
    while (NC > 1 && (size_t)(NC + 1) * unit > ws_size) NC >>= 1;
    const int sLen = SEQ / NC;

    float* KVf = (float*)d_ws;
    float* Ksf = KVf + 32 * 4096;
    float* pKV = Ksf + 32 * 64;
    float* pKs = pKV + (size_t)NC * 32 * 4096;

    hipLaunchKernelGGL(k_phase1, dim3(32 * NC), dim3(256), 0, stream, K, V, pKV, pKs, NC, sLen);
    switch (NC) {
        case 16: hipLaunchKernelGGL(k_reduceT<16>, dim3(256), dim3(128), 0, stream, pKV, pKs, KVf, Ksf); break;
        case 8:  hipLaunchKernelGGL(k_reduceT<8>,  dim3(256), dim3(128), 0, stream, pKV, pKs, KVf, Ksf); break;
        case 4:  hipLaunchKernelGGL(k_reduceT<4>,  dim3(256), dim3(128), 0, stream, pKV, pKs, KVf, Ksf); break;
        default: hipLaunchKernelGGL(k_reduceG, dim3(256), dim3(128), 0, stream, pKV, pKs, KVf, Ksf, NC); break;
    }
    hipLaunchKernelGGL(k_phase2, dim3(512), dim3(256), 0, stream, Q, KVf, Ksf, out);
}